// Round 8
// baseline (2640.881 us; speedup 1.0000x reference)
//
#include <hip/hip_runtime.h>
#include <cstddef>
#include <cstdint>

typedef _Float16 f16;
typedef _Float16 f16x4 __attribute__((ext_vector_type(4)));
typedef _Float16 f16x8 __attribute__((ext_vector_type(8)));
typedef float f32x4 __attribute__((ext_vector_type(4)));
typedef float f32x16 __attribute__((ext_vector_type(16)));

#define AS1 __attribute__((address_space(1)))
#define AS3 __attribute__((address_space(3)))

// ---------------------------------------------------------------------------
// CapsuleNet forward.  conv2 = f16 MFMA implicit GEMM, split-K=4,
// block tile 128oc x 128n, wave 64x64.  B staged via global_load_lds (32KB
// dbuf, XOR-swizzled); A streamed L2->registers (reg-dbuf, coalesced via
// w16t[kk][chunk][oc][8] layout).  Counted vmcnt(12) + raw s_barrier.
// ws: y16 f16[512*400*256] | w16t f16[81*32*256*8] | p4 f32[4][512*256*36]
//     | u f32[512*1152*8] | logits f32[5120]
// ---------------------------------------------------------------------------

__device__ __forceinline__ float wave_max(float v) {
#pragma unroll
  for (int m = 1; m < 64; m <<= 1) v = fmaxf(v, __shfl_xor(v, m, 64));
  return v;
}
__device__ __forceinline__ float wave_sum(float v) {
#pragma unroll
  for (int m = 1; m < 64; m <<= 1) v += __shfl_xor(v, m, 64);
  return v;
}

// ---------------- Conv1: x(512,1,28,28) * w(256,1,9,9) + b -> y16[b][px][ic] f16
__global__ __launch_bounds__(256) void conv1_kernel(
    const float* __restrict__ x, const float* __restrict__ w,
    const float* __restrict__ bias, f16* __restrict__ y16) {
  const int b   = blockIdx.x;
  const int oc0 = blockIdx.y * 64;
  const int t   = threadIdx.x;
  const int tx  = t & 15;
  const int ty  = t >> 4;
  const int oxg = ty & 3;
  const int oy0 = ty >> 2;

  __shared__ float x_s[784];
  __shared__ float w_s[81][68];

  for (int idx = t; idx < 784; idx += 256) x_s[idx] = x[b * 784 + idx];
  for (int idx = t; idx < 64 * 81; idx += 256) {
    const int oc_l = idx / 81, k = idx % 81;
    w_s[k][oc_l] = w[(oc0 + oc_l) * 81 + k];
  }
  __syncthreads();

  float bz[4];
#pragma unroll
  for (int j = 0; j < 4; ++j) bz[j] = bias[oc0 + tx * 4 + j];

  for (int m = 0; m < 5; ++m) {
    const int oy = oy0 + m * 4;
    float acc[4][5];
#pragma unroll
    for (int j = 0; j < 4; ++j)
#pragma unroll
      for (int pp = 0; pp < 5; ++pp) acc[j][pp] = 0.f;

#pragma unroll
    for (int ky = 0; ky < 9; ++ky) {
      float xv[13];
      const int base = (oy + ky) * 28 + oxg * 5;
#pragma unroll
      for (int jj = 0; jj < 13; ++jj) xv[jj] = x_s[base + jj];
#pragma unroll
      for (int kx = 0; kx < 9; ++kx) {
        const float4 w4 = *reinterpret_cast<const float4*>(&w_s[ky * 9 + kx][tx * 4]);
#pragma unroll
        for (int pp = 0; pp < 5; ++pp) {
          const float xval = xv[kx + pp];
          acc[0][pp] += w4.x * xval;
          acc[1][pp] += w4.y * xval;
          acc[2][pp] += w4.z * xval;
          acc[3][pp] += w4.w * xval;
        }
      }
    }
#pragma unroll
    for (int pp = 0; pp < 5; ++pp) {
      f16x4 st;
#pragma unroll
      for (int j = 0; j < 4; ++j) st[j] = (f16)(acc[j][pp] + bz[j]);
      const int px = oy * 20 + oxg * 5 + pp;
      *(f16x4*)&y16[((size_t)b * 400 + px) * 256 + oc0 + tx * 4] = st;
    }
  }
}

// ---------------- weight prep: prim_w[oc][ic][81] f32 ->
//   w16t[kk81][chunk32][oc256][8]  (chunk = ic/8; A-frag = coalesced 16B/lane)
__global__ __launch_bounds__(256) void wprep_kernel(const float* __restrict__ w,
                                                    f16* __restrict__ w16t) {
  const int idx = blockIdx.x * 256 + threadIdx.x;  // 81*32*256 = 663552
  const int kk  = idx >> 13;
  const int rem = idx & 8191;
  const int icg = rem >> 8;   // chunk 0..31
  const int oc  = rem & 255;
  f16x8 v;
#pragma unroll
  for (int j = 0; j < 8; ++j)
    v[j] = (f16)w[((size_t)(oc * 256 + icg * 8 + j)) * 81 + kk];
  *(f16x8*)&w16t[(((size_t)kk * 32 + icg) * 256 + oc) * 8] = v;
}

// ---------------- Conv2 MFMA
// block: M=128 oc x N=128 n, K-step=64, 81 steps.  4 waves 2Mx2N, wave 64x64.
// B in LDS (16KB/buf, dbuf 32KB, XOR-swizzle seg^=row&7 on src + read).
// A direct L2->reg: 8 coalesced 16B loads/wave/step, reg double-buffered.
// grid = variant(8: mtile*4+ks) * 144 ntiles; bid%8 == ntile%8 (XCD co-loc).
__global__ __launch_bounds__(256, 3) void conv2_mfma(
    const f16* __restrict__ y16, const f16* __restrict__ w16t,
    float* __restrict__ p4) {
  const int h       = blockIdx.x;
  const int ntile   = h % 144;
  const int variant = h / 144;
  const int mtile   = variant >> 2;
  const int ks      = variant & 3;
  const int oc0     = mtile * 128;
  const int cicb    = ks * 64;

  const int tid  = threadIdx.x;
  const int lane = tid & 63;
  const int wave = tid >> 6;
  const int l31  = lane & 31;
  const int hi   = lane >> 5;      // 0/1
  const int wm   = wave >> 1;      // M half
  const int wn   = wave & 1;       // N half

  __shared__ char smem[32768];

  // ---- B staging: 16 row-groups of 8 rows, 4 gload_lds per wave
  const int lr   = lane >> 3;                    // row within 8-row group
  const int swz  = ((lane & 7) ^ (lr & 7)) * 8;  // swizzled ic offset (f16)
  const f16* bPtr[4];
  uint32_t bLoff[4];
#pragma unroll
  for (int q = 0; q < 4; ++q) {
    const int g  = wave * 4 + q;
    const int n  = ntile * 128 + g * 8 + lr;
    const int b  = n / 36;
    const int op = n - b * 36;
    const int oy = op / 6;
    const int ox = op - oy * 6;
    bPtr[q]  = y16 + ((size_t)b * 400 + 40 * oy + 2 * ox) * 256 + cicb + swz;
    bLoff[q] = (uint32_t)__builtin_amdgcn_readfirstlane(g * 1024);
  }

  // ---- A base: addr(f16) = kk*65536 + (ks*8 + kc*2 + hi)*2048 + oc*8
  const int aBase = (ks * 8 + hi) * 2048 + (oc0 + wm * 64 + l31) * 8;

  f32x16 acc00, acc01, acc10, acc11;
#pragma unroll
  for (int r = 0; r < 16; ++r) {
    acc00[r] = 0.f; acc01[r] = 0.f; acc10[r] = 0.f; acc11[r] = 0.f;
  }

  auto stage = [&](int bb, int kkn) {
    const int ky    = kkn / 9;
    const int kx    = kkn - ky * 9;
    const int koffB = (20 * ky + kx) * 256;
#pragma unroll
    for (int q = 0; q < 4; ++q)
      __builtin_amdgcn_global_load_lds(
          (const AS1 uint32_t*)(bPtr[q] + koffB),
          (AS3 uint32_t*)((AS3 char*)smem + bb + bLoff[q]), 16, 0, 0);
  };

  auto loadA = [&](f16x8 (&dst)[8], int kkn) {
    const f16* bp = w16t + (size_t)kkn * 65536 + aBase;
#pragma unroll
    for (int kc = 0; kc < 4; ++kc)
#pragma unroll
      for (int af = 0; af < 2; ++af)
        dst[kc * 2 + af] = *(const f16x8*)(bp + kc * 4096 + af * 256);
  };

  const int rowB  = (wn * 64 + l31) * 128;
  const int sbase = l31 & 7;

  auto compute = [&](const char* bufp, const f16x8 (&aC)[8]) {
#pragma unroll
    for (int kc = 0; kc < 4; ++kc) {
      const int sw = (((kc * 2 + hi) ^ sbase) << 4);
      const f16x8 b0 = *(const f16x8*)(bufp + rowB + sw);
      const f16x8 b1 = *(const f16x8*)(bufp + rowB + 32 * 128 + sw);
      acc00 = __builtin_amdgcn_mfma_f32_32x32x16_f16(aC[kc * 2 + 0], b0, acc00, 0, 0, 0);
      acc01 = __builtin_amdgcn_mfma_f32_32x32x16_f16(aC[kc * 2 + 0], b1, acc01, 0, 0, 0);
      acc10 = __builtin_amdgcn_mfma_f32_32x32x16_f16(aC[kc * 2 + 1], b0, acc10, 0, 0, 0);
      acc11 = __builtin_amdgcn_mfma_f32_32x32x16_f16(aC[kc * 2 + 1], b1, acc11, 0, 0, 0);
    }
  };

  f16x8 aA[8], aB[8];
  stage(0, 0);       // 4 outstanding
  loadA(aA, 0);      // 12 outstanding

  for (int kk = 0; kk < 81; ++kk) {
    const char* bufp = smem + (kk & 1) * 16384;
    if (kk < 80) {
      stage((kk & 1) ? 0 : 16384, kk + 1);
      if (kk & 1) loadA(aA, kk + 1); else loadA(aB, kk + 1);
      __builtin_amdgcn_sched_barrier(0);
      asm volatile("s_waitcnt vmcnt(12)" ::: "memory");  // prev 12 landed
    } else {
      asm volatile("s_waitcnt vmcnt(0)" ::: "memory");
    }
    __builtin_amdgcn_s_barrier();  // cur B visible to all waves

    __builtin_amdgcn_s_setprio(1);
    if (kk & 1) compute(bufp, aB); else compute(bufp, aA);
    __builtin_amdgcn_s_setprio(0);
    __builtin_amdgcn_s_barrier();  // reads of cur done -> restage allowed
  }

  // ---- epilogue: C[m][n]: oc_m = (r&3)+8*(r>>2)+4*hi, n = l31
  float* pk = p4 + (size_t)ks * 4718592;
#pragma unroll
  for (int af = 0; af < 2; ++af) {
#pragma unroll
    for (int bf = 0; bf < 2; ++bf) {
      const f32x16 a = af ? (bf ? acc11 : acc10) : (bf ? acc01 : acc00);
      const int n  = ntile * 128 + wn * 64 + bf * 32 + l31;
      const int b  = n / 36;
      const int op = n - b * 36;
      float* pb = pk + (size_t)b * 9216 + op;
      const int ocb = oc0 + wm * 64 + af * 32 + 4 * hi;
#pragma unroll
      for (int r = 0; r < 16; ++r) {
        const int oc = ocb + (r & 3) + 8 * (r >> 2);
        pb[oc * 36] = a[r];
      }
    }
  }
}

// ---------------- squash: sum 4 K-partials + bias, squash -> u(512,1152,8)
__global__ __launch_bounds__(256) void squash_kernel(const float* __restrict__ p4,
                                                     const float* __restrict__ bias,
                                                     float* __restrict__ u) {
  const int idx = blockIdx.x * 256 + threadIdx.x;
  if (idx >= 512 * 1152) return;
  const int b = idx / 1152;
  const int r = idx % 1152;
  const int c2 = r / 36;
  const int s  = r % 36;
  const size_t base = (size_t)b * 9216 + c2 * 36 + s;
  float tv[8];
  float sn = 0.f;
#pragma unroll
  for (int g = 0; g < 8; ++g) {
    const size_t off = base + (size_t)g * 32 * 36;
    float t = p4[off] + p4[off + 4718592] + p4[off + 2 * 4718592] +
              p4[off + 3 * 4718592] + bias[g * 32 + c2];
    tv[g] = t;
    sn += t * t;
  }
  const float scale = sn / ((1.f + sn) * sqrtf(sn));
  float* up = u + (size_t)idx * 8;
#pragma unroll
  for (int g = 0; g < 8; ++g) up[g] = tv[g] * scale;
}

// ---------------- routing: per (b,c) block. priors (1152x16) in registers.
__global__ __launch_bounds__(256) void routing_kernel(const float* __restrict__ u,
                                                      const float* __restrict__ rw,
                                                      float* __restrict__ logits) {
  const int b    = blockIdx.x;
  const int c    = blockIdx.y;
  const int t    = threadIdx.x;
  const int og   = t & 3;
  const int rg   = t >> 2;
  const int lane = t & 63;
  const int wid  = t >> 6;

  __shared__ float u_s[1152 * 9];
  __shared__ float blog_s[1152];
  __shared__ float red[8];
  __shared__ float sred[64];

  for (int idx = t; idx < 1152 * 8; idx += 256)
    u_s[(idx >> 3) * 9 + (idx & 7)] = u[(size_t)b * 9216 + idx];
  for (int idx = t; idx < 1152; idx += 256) blog_s[idx] = 0.f;
  __syncthreads();

  float pr[18][4];
  const float* rwc = rw + (size_t)c * 1152 * 128;
#pragma unroll
  for (int k = 0; k < 18; ++k) {
    const int r = rg + 64 * k;
    float a0 = 0.f, a1 = 0.f, a2 = 0.f, a3 = 0.f;
#pragma unroll
    for (int i = 0; i < 8; ++i) {
      const float uv = u_s[r * 9 + i];
      const float4 w4 = *reinterpret_cast<const float4*>(rwc + (size_t)r * 128 + i * 16 + og * 4);
      a0 += uv * w4.x; a1 += uv * w4.y; a2 += uv * w4.z; a3 += uv * w4.w;
    }
    pr[k][0] = a0; pr[k][1] = a1; pr[k][2] = a2; pr[k][3] = a3;
  }

  float sn = 0.f;
  float vj[4] = {0.f, 0.f, 0.f, 0.f};

  for (int it = 0; it < 3; ++it) {
    float lmax = -3.4e38f;
    for (int idx = t; idx < 1152; idx += 256) lmax = fmaxf(lmax, blog_s[idx]);
    lmax = wave_max(lmax);
    if (lane == 0) red[wid] = lmax;
    __syncthreads();
    const float gmax = fmaxf(fmaxf(red[0], red[1]), fmaxf(red[2], red[3]));
    float lsum = 0.f;
    for (int idx = t; idx < 1152; idx += 256) lsum += expf(blog_s[idx] - gmax);
    lsum = wave_sum(lsum);
    if (lane == 0) red[4 + wid] = lsum;
    __syncthreads();
    const float ginv = 1.f / (red[4] + red[5] + red[6] + red[7]);

    float sp0 = 0.f, sp1 = 0.f, sp2 = 0.f, sp3 = 0.f;
#pragma unroll
    for (int k = 0; k < 18; ++k) {
      const int r = rg + 64 * k;
      const float pb = expf(blog_s[r] - gmax) * ginv;
      sp0 += pr[k][0] * pb; sp1 += pr[k][1] * pb;
      sp2 += pr[k][2] * pb; sp3 += pr[k][3] * pb;
    }
#pragma unroll
    for (int m = 4; m < 64; m <<= 1) {
      sp0 += __shfl_xor(sp0, m, 64);
      sp1 += __shfl_xor(sp1, m, 64);
      sp2 += __shfl_xor(sp2, m, 64);
      sp3 += __shfl_xor(sp3, m, 64);
    }
    if (lane < 4) {
      sred[wid * 16 + lane * 4 + 0] = sp0;
      sred[wid * 16 + lane * 4 + 1] = sp1;
      sred[wid * 16 + lane * 4 + 2] = sp2;
      sred[wid * 16 + lane * 4 + 3] = sp3;
    }
    __syncthreads();

    sn = 0.f;
#pragma unroll
    for (int o = 0; o < 16; ++o) {
      const float sv = sred[o] + sred[16 + o] + sred[32 + o] + sred[48 + o];
      sn += sv * sv;
    }
    const float scale = sn / ((1.f + sn) * sqrtf(sn));
#pragma unroll
    for (int j = 0; j < 4; ++j) {
      const int o = og * 4 + j;
      vj[j] = (sred[o] + sred[16 + o] + sred[32 + o] + sred[48 + o]) * scale;
    }

    if (it < 2) {
#pragma unroll
      for (int k = 0; k < 18; ++k) {
        float bp = pr[k][0] * vj[0] + pr[k][1] * vj[1] + pr[k][2] * vj[2] + pr[k][3] * vj[3];
        bp += __shfl_xor(bp, 1, 64);
        bp += __shfl_xor(bp, 2, 64);
        if (og == 0) blog_s[rg + 64 * k] += bp;
      }
      __syncthreads();
    }
  }
  if (t == 0) logits[b * 10 + c] = sn / (1.f + sn);
}

// ---------------- final softmax over 10 classes
__global__ __launch_bounds__(256) void out_softmax_kernel(const float* __restrict__ logits,
                                                          float* __restrict__ out) {
  const int b = blockIdx.x * 256 + threadIdx.x;
  if (b >= 512) return;
  float l[10];
  float mx = -3.4e38f;
#pragma unroll
  for (int cc = 0; cc < 10; ++cc) {
    l[cc] = logits[b * 10 + cc];
    mx = fmaxf(mx, l[cc]);
  }
  float s = 0.f;
#pragma unroll
  for (int cc = 0; cc < 10; ++cc) {
    l[cc] = expf(l[cc] - mx);
    s += l[cc];
  }
  const float inv = 1.f / s;
#pragma unroll
  for (int cc = 0; cc < 10; ++cc) out[b * 10 + cc] = l[cc] * inv;
}

extern "C" void kernel_launch(void* const* d_in, const int* in_sizes, int n_in,
                              void* d_out, int out_size, void* d_ws, size_t ws_size,
                              hipStream_t stream) {
  const float* x       = (const float*)d_in[0];
  const float* conv_w  = (const float*)d_in[1];
  const float* conv_b  = (const float*)d_in[2];
  const float* prim_w  = (const float*)d_in[3];
  const float* prim_b  = (const float*)d_in[4];
  const float* route_w = (const float*)d_in[5];
  float* out = (float*)d_out;

  f16* y16      = (f16*)d_ws;               // 52,428,800 halves (104.9 MB)
  f16* w16t     = y16 + 52428800;           //  5,308,416 halves ( 10.6 MB)
  float* p4     = (float*)(w16t + 5308416); //  4 x 4,718,592 f32 ( 75.5 MB)
  float* u      = p4 + 4 * 4718592;         //  4,718,592 f32     ( 18.9 MB)
  float* logits = u + 4718592;              //  5,120 f32

  conv1_kernel<<<dim3(512, 4), 256, 0, stream>>>(x, conv_w, conv_b, y16);
  wprep_kernel<<<2592, 256, 0, stream>>>(prim_w, w16t);
  conv2_mfma<<<1152, 256, 0, stream>>>(y16, w16t, p4);
  squash_kernel<<<(512 * 1152 + 255) / 256, 256, 0, stream>>>(p4, prim_b, u);
  routing_kernel<<<dim3(512, 10), 256, 0, stream>>>(u, route_w, logits);
  out_softmax_kernel<<<2, 256, 0, stream>>>(logits, out);
}

// Round 9
// 686.236 us; speedup vs baseline: 3.8484x; 3.8484x over previous
//
#include <hip/hip_runtime.h>
#include <cstddef>
#include <cstdint>

typedef _Float16 f16;
typedef _Float16 f16x4 __attribute__((ext_vector_type(4)));
typedef _Float16 f16x8 __attribute__((ext_vector_type(8)));
typedef float f32x4 __attribute__((ext_vector_type(4)));
typedef float f32x16 __attribute__((ext_vector_type(16)));

#define AS1 __attribute__((address_space(1)))
#define AS3 __attribute__((address_space(3)))

// ---------------------------------------------------------------------------
// CapsuleNet forward.  conv2 = R6-exact f16 MFMA implicit GEMM (proven 239us).
// routing reads route_w as f16 (halves its 3 GB L2 stream).
// ws: y16 f16[512*400*256] | w16 f16[81*256*256] | p4 f32[4][512*256*36]
//     | u f32[512*1152*8] | rw16 f16[10*1152*128] | logits f32[5120]
// ---------------------------------------------------------------------------

__device__ __forceinline__ float wave_max(float v) {
#pragma unroll
  for (int m = 1; m < 64; m <<= 1) v = fmaxf(v, __shfl_xor(v, m, 64));
  return v;
}
__device__ __forceinline__ float wave_sum(float v) {
#pragma unroll
  for (int m = 1; m < 64; m <<= 1) v += __shfl_xor(v, m, 64);
  return v;
}

// ---------------- Conv1: x(512,1,28,28) * w(256,1,9,9) + b -> y16[b][px][ic] f16
__global__ __launch_bounds__(256) void conv1_kernel(
    const float* __restrict__ x, const float* __restrict__ w,
    const float* __restrict__ bias, f16* __restrict__ y16) {
  const int b   = blockIdx.x;
  const int oc0 = blockIdx.y * 64;
  const int t   = threadIdx.x;
  const int tx  = t & 15;
  const int ty  = t >> 4;
  const int oxg = ty & 3;
  const int oy0 = ty >> 2;

  __shared__ float x_s[784];
  __shared__ float w_s[81][68];

  for (int idx = t; idx < 784; idx += 256) x_s[idx] = x[b * 784 + idx];
  for (int idx = t; idx < 64 * 81; idx += 256) {
    const int oc_l = idx / 81, k = idx % 81;
    w_s[k][oc_l] = w[(oc0 + oc_l) * 81 + k];
  }
  __syncthreads();

  float bz[4];
#pragma unroll
  for (int j = 0; j < 4; ++j) bz[j] = bias[oc0 + tx * 4 + j];

  for (int m = 0; m < 5; ++m) {
    const int oy = oy0 + m * 4;
    float acc[4][5];
#pragma unroll
    for (int j = 0; j < 4; ++j)
#pragma unroll
      for (int pp = 0; pp < 5; ++pp) acc[j][pp] = 0.f;

#pragma unroll
    for (int ky = 0; ky < 9; ++ky) {
      float xv[13];
      const int base = (oy + ky) * 28 + oxg * 5;
#pragma unroll
      for (int jj = 0; jj < 13; ++jj) xv[jj] = x_s[base + jj];
#pragma unroll
      for (int kx = 0; kx < 9; ++kx) {
        const float4 w4 = *reinterpret_cast<const float4*>(&w_s[ky * 9 + kx][tx * 4]);
#pragma unroll
        for (int pp = 0; pp < 5; ++pp) {
          const float xval = xv[kx + pp];
          acc[0][pp] += w4.x * xval;
          acc[1][pp] += w4.y * xval;
          acc[2][pp] += w4.z * xval;
          acc[3][pp] += w4.w * xval;
        }
      }
    }
#pragma unroll
    for (int pp = 0; pp < 5; ++pp) {
      f16x4 st;
#pragma unroll
      for (int j = 0; j < 4; ++j) st[j] = (f16)(acc[j][pp] + bz[j]);
      const int px = oy * 20 + oxg * 5 + pp;
      *(f16x4*)&y16[((size_t)b * 400 + px) * 256 + oc0 + tx * 4] = st;
    }
  }
}

// ---------------- weight prep: prim_w[oc][ic][81] f32 -> w16[k81][oc][ic] f16
__global__ __launch_bounds__(256) void wprep_kernel(const float* __restrict__ w,
                                                    f16* __restrict__ w16) {
  const int idx = blockIdx.x * 256 + threadIdx.x;
  const int kk  = idx >> 13;
  const int rem = idx & 8191;
  const int oc  = rem >> 5;
  const int icg = rem & 31;
  f16x8 v;
#pragma unroll
  for (int j = 0; j < 8; ++j)
    v[j] = (f16)w[((size_t)(oc * 256 + icg * 8 + j)) * 81 + kk];
  *(f16x8*)&w16[((size_t)kk * 256 + oc) * 256 + icg * 8] = v;
}

// ---------------- route_w prep: f32 -> f16 (same layout, contiguous)
__global__ __launch_bounds__(256) void wprep_rw(const float* __restrict__ rw,
                                                f16* __restrict__ rw16) {
  const int idx = (blockIdx.x * 256 + threadIdx.x) * 8;  // 1,474,560 total
  const float4 a = *(const float4*)(rw + idx);
  const float4 b = *(const float4*)(rw + idx + 4);
  f16x8 v;
  v[0] = (f16)a.x; v[1] = (f16)a.y; v[2] = (f16)a.z; v[3] = (f16)a.w;
  v[4] = (f16)b.x; v[5] = (f16)b.y; v[6] = (f16)b.z; v[7] = (f16)b.w;
  *(f16x8*)&rw16[idx] = v;
}

// ---------------- Conv2 MFMA (R6-exact, proven)
// block: M=128 oc x N=128 n, K-step=64 (one ic-window/tap), 81 steps.
// 4 waves 2Mx2N, wave tile 64x64: per K16 chunk {2 A, 2 B reads -> 4 MFMA}.
// LDS per buf: A 128x128B @0 (16KB), B @16384 (16KB); dbuf = 64KB.
// Swizzle: 16B-seg' = seg ^ (row&7) on global src + ds_read.
__global__ __launch_bounds__(256, 2) void conv2_mfma(
    const f16* __restrict__ y16, const f16* __restrict__ w16,
    float* __restrict__ p4) {
  const int h       = blockIdx.x;
  const int ntile   = h % 144;
  const int variant = h / 144;
  const int mtile   = variant >> 2;
  const int ks      = variant & 3;
  const int oc0     = mtile * 128;
  const int cicb    = ks * 64;

  const int tid  = threadIdx.x;
  const int lane = tid & 63;
  const int wave = tid >> 6;
  const int l31  = lane & 31;
  const int hi   = lane >> 5;
  const int wm   = wave >> 1;
  const int wn   = wave & 1;

  __shared__ char smem[65536];

  const int lr   = lane >> 3;
  const int swz  = ((lane & 7) ^ (lr & 7)) * 8;
  const f16* aPtr[4];
  uint32_t aLoff[4];
#pragma unroll
  for (int q = 0; q < 4; ++q) {
    const int g  = wave * 4 + q;
    const int oc = oc0 + g * 8 + lr;
    aPtr[q]  = w16 + (size_t)oc * 256 + cicb + swz;
    aLoff[q] = (uint32_t)__builtin_amdgcn_readfirstlane(g * 1024);
  }
  const f16* bPtr[4];
  uint32_t bLoff[4];
#pragma unroll
  for (int q = 0; q < 4; ++q) {
    const int g  = wave * 4 + q;
    const int n  = ntile * 128 + g * 8 + lr;
    const int b  = n / 36;
    const int op = n - b * 36;
    const int oy = op / 6;
    const int ox = op - oy * 6;
    bPtr[q]  = y16 + ((size_t)b * 400 + 40 * oy + 2 * ox) * 256 + cicb + swz;
    bLoff[q] = (uint32_t)__builtin_amdgcn_readfirstlane(16384 + g * 1024);
  }

  f32x16 acc00, acc01, acc10, acc11;
#pragma unroll
  for (int r = 0; r < 16; ++r) {
    acc00[r] = 0.f; acc01[r] = 0.f; acc10[r] = 0.f; acc11[r] = 0.f;
  }

  auto stage = [&](int bb, int kkn) {
    const int ky    = kkn / 9;
    const int kx    = kkn - ky * 9;
    const int koffB = (20 * ky + kx) * 256;
    const size_t koffA = (size_t)kkn * 65536;
#pragma unroll
    for (int q = 0; q < 4; ++q)
      __builtin_amdgcn_global_load_lds(
          (const AS1 uint32_t*)(aPtr[q] + koffA),
          (AS3 uint32_t*)((AS3 char*)smem + bb + aLoff[q]), 16, 0, 0);
#pragma unroll
    for (int q = 0; q < 4; ++q)
      __builtin_amdgcn_global_load_lds(
          (const AS1 uint32_t*)(bPtr[q] + koffB),
          (AS3 uint32_t*)((AS3 char*)smem + bb + bLoff[q]), 16, 0, 0);
  };

  const int rowA  = (wm * 64 + l31) * 128;
  const int rowB  = 16384 + (wn * 64 + l31) * 128;
  const int sbase = l31 & 7;

  stage(0, 0);

  for (int kk = 0; kk < 81; ++kk) {
    const int cur = (kk & 1) * 32768;
    if (kk < 80) {
      stage(cur ^ 32768, kk + 1);
      asm volatile("s_waitcnt vmcnt(8)" ::: "memory");
    } else {
      asm volatile("s_waitcnt vmcnt(0)" ::: "memory");
    }
    __builtin_amdgcn_s_barrier();

    const char* bufp = smem + cur;
    __builtin_amdgcn_s_setprio(1);
#pragma unroll
    for (int kc = 0; kc < 4; ++kc) {
      const int sw = (((kc * 2 + hi) ^ sbase) << 4);
      const f16x8 a0 = *(const f16x8*)(bufp + rowA + sw);
      const f16x8 a1 = *(const f16x8*)(bufp + rowA + 32 * 128 + sw);
      const f16x8 b0 = *(const f16x8*)(bufp + rowB + sw);
      const f16x8 b1 = *(const f16x8*)(bufp + rowB + 32 * 128 + sw);
      acc00 = __builtin_amdgcn_mfma_f32_32x32x16_f16(a0, b0, acc00, 0, 0, 0);
      acc01 = __builtin_amdgcn_mfma_f32_32x32x16_f16(a0, b1, acc01, 0, 0, 0);
      acc10 = __builtin_amdgcn_mfma_f32_32x32x16_f16(a1, b0, acc10, 0, 0, 0);
      acc11 = __builtin_amdgcn_mfma_f32_32x32x16_f16(a1, b1, acc11, 0, 0, 0);
    }
    __builtin_amdgcn_s_setprio(0);
    __builtin_amdgcn_s_barrier();
  }

  float* pk = p4 + (size_t)ks * 4718592;
#pragma unroll
  for (int af = 0; af < 2; ++af) {
#pragma unroll
    for (int bf = 0; bf < 2; ++bf) {
      const f32x16 a = af ? (bf ? acc11 : acc10) : (bf ? acc01 : acc00);
      const int n  = ntile * 128 + wn * 64 + bf * 32 + l31;
      const int b  = n / 36;
      const int op = n - b * 36;
      float* pb = pk + (size_t)b * 9216 + op;
      const int ocb = oc0 + wm * 64 + af * 32 + 4 * hi;
#pragma unroll
      for (int r = 0; r < 16; ++r) {
        const int oc = ocb + (r & 3) + 8 * (r >> 2);
        pb[oc * 36] = a[r];
      }
    }
  }
}

// ---------------- squash: sum 4 K-partials + bias, squash -> u(512,1152,8)
__global__ __launch_bounds__(256) void squash_kernel(const float* __restrict__ p4,
                                                     const float* __restrict__ bias,
                                                     float* __restrict__ u) {
  const int idx = blockIdx.x * 256 + threadIdx.x;
  if (idx >= 512 * 1152) return;
  const int b = idx / 1152;
  const int r = idx % 1152;
  const int c2 = r / 36;
  const int s  = r % 36;
  const size_t base = (size_t)b * 9216 + c2 * 36 + s;
  float tv[8];
  float sn = 0.f;
#pragma unroll
  for (int g = 0; g < 8; ++g) {
    const size_t off = base + (size_t)g * 32 * 36;
    float t = p4[off] + p4[off + 4718592] + p4[off + 2 * 4718592] +
              p4[off + 3 * 4718592] + bias[g * 32 + c2];
    tv[g] = t;
    sn += t * t;
  }
  const float scale = sn / ((1.f + sn) * sqrtf(sn));
  float* up = u + (size_t)idx * 8;
#pragma unroll
  for (int g = 0; g < 8; ++g) up[g] = tv[g] * scale;
}

// ---------------- routing: per (b,c) block; route_w in f16.
__global__ __launch_bounds__(256) void routing_kernel(const float* __restrict__ u,
                                                      const f16* __restrict__ rw16,
                                                      float* __restrict__ logits) {
  const int b    = blockIdx.x;
  const int c    = blockIdx.y;
  const int t    = threadIdx.x;
  const int og   = t & 3;
  const int rg   = t >> 2;
  const int lane = t & 63;
  const int wid  = t >> 6;

  __shared__ float u_s[1152 * 9];
  __shared__ float blog_s[1152];
  __shared__ float red[8];
  __shared__ float sred[64];

  for (int idx = t; idx < 1152 * 8; idx += 256)
    u_s[(idx >> 3) * 9 + (idx & 7)] = u[(size_t)b * 9216 + idx];
  for (int idx = t; idx < 1152; idx += 256) blog_s[idx] = 0.f;
  __syncthreads();

  float pr[18][4];
  const f16* rwc = rw16 + (size_t)c * 1152 * 128;
#pragma unroll
  for (int k = 0; k < 18; ++k) {
    const int r = rg + 64 * k;
    float a0 = 0.f, a1 = 0.f, a2 = 0.f, a3 = 0.f;
#pragma unroll
    for (int i = 0; i < 8; ++i) {
      const float uv = u_s[r * 9 + i];
      const f16x4 w4 = *reinterpret_cast<const f16x4*>(rwc + (size_t)r * 128 + i * 16 + og * 4);
      a0 += uv * (float)w4[0]; a1 += uv * (float)w4[1];
      a2 += uv * (float)w4[2]; a3 += uv * (float)w4[3];
    }
    pr[k][0] = a0; pr[k][1] = a1; pr[k][2] = a2; pr[k][3] = a3;
  }

  float sn = 0.f;
  float vj[4] = {0.f, 0.f, 0.f, 0.f};

  for (int it = 0; it < 3; ++it) {
    float lmax = -3.4e38f;
    for (int idx = t; idx < 1152; idx += 256) lmax = fmaxf(lmax, blog_s[idx]);
    lmax = wave_max(lmax);
    if (lane == 0) red[wid] = lmax;
    __syncthreads();
    const float gmax = fmaxf(fmaxf(red[0], red[1]), fmaxf(red[2], red[3]));
    float lsum = 0.f;
    for (int idx = t; idx < 1152; idx += 256) lsum += expf(blog_s[idx] - gmax);
    lsum = wave_sum(lsum);
    if (lane == 0) red[4 + wid] = lsum;
    __syncthreads();
    const float ginv = 1.f / (red[4] + red[5] + red[6] + red[7]);

    float sp0 = 0.f, sp1 = 0.f, sp2 = 0.f, sp3 = 0.f;
#pragma unroll
    for (int k = 0; k < 18; ++k) {
      const int r = rg + 64 * k;
      const float pb = expf(blog_s[r] - gmax) * ginv;
      sp0 += pr[k][0] * pb; sp1 += pr[k][1] * pb;
      sp2 += pr[k][2] * pb; sp3 += pr[k][3] * pb;
    }
#pragma unroll
    for (int m = 4; m < 64; m <<= 1) {
      sp0 += __shfl_xor(sp0, m, 64);
      sp1 += __shfl_xor(sp1, m, 64);
      sp2 += __shfl_xor(sp2, m, 64);
      sp3 += __shfl_xor(sp3, m, 64);
    }
    if (lane < 4) {
      sred[wid * 16 + lane * 4 + 0] = sp0;
      sred[wid * 16 + lane * 4 + 1] = sp1;
      sred[wid * 16 + lane * 4 + 2] = sp2;
      sred[wid * 16 + lane * 4 + 3] = sp3;
    }
    __syncthreads();

    sn = 0.f;
#pragma unroll
    for (int o = 0; o < 16; ++o) {
      const float sv = sred[o] + sred[16 + o] + sred[32 + o] + sred[48 + o];
      sn += sv * sv;
    }
    const float scale = sn / ((1.f + sn) * sqrtf(sn));
#pragma unroll
    for (int j = 0; j < 4; ++j) {
      const int o = og * 4 + j;
      vj[j] = (sred[o] + sred[16 + o] + sred[32 + o] + sred[48 + o]) * scale;
    }

    if (it < 2) {
#pragma unroll
      for (int k = 0; k < 18; ++k) {
        float bp = pr[k][0] * vj[0] + pr[k][1] * vj[1] + pr[k][2] * vj[2] + pr[k][3] * vj[3];
        bp += __shfl_xor(bp, 1, 64);
        bp += __shfl_xor(bp, 2, 64);
        if (og == 0) blog_s[rg + 64 * k] += bp;
      }
      __syncthreads();
    }
  }
  if (t == 0) logits[b * 10 + c] = sn / (1.f + sn);
}

// ---------------- final softmax over 10 classes
__global__ __launch_bounds__(256) void out_softmax_kernel(const float* __restrict__ logits,
                                                          float* __restrict__ out) {
  const int b = blockIdx.x * 256 + threadIdx.x;
  if (b >= 512) return;
  float l[10];
  float mx = -3.4e38f;
#pragma unroll
  for (int cc = 0; cc < 10; ++cc) {
    l[cc] = logits[b * 10 + cc];
    mx = fmaxf(mx, l[cc]);
  }
  float s = 0.f;
#pragma unroll
  for (int cc = 0; cc < 10; ++cc) {
    l[cc] = expf(l[cc] - mx);
    s += l[cc];
  }
  const float inv = 1.f / s;
#pragma unroll
  for (int cc = 0; cc < 10; ++cc) out[b * 10 + cc] = l[cc] * inv;
}

extern "C" void kernel_launch(void* const* d_in, const int* in_sizes, int n_in,
                              void* d_out, int out_size, void* d_ws, size_t ws_size,
                              hipStream_t stream) {
  const float* x       = (const float*)d_in[0];
  const float* conv_w  = (const float*)d_in[1];
  const float* conv_b  = (const float*)d_in[2];
  const float* prim_w  = (const float*)d_in[3];
  const float* prim_b  = (const float*)d_in[4];
  const float* route_w = (const float*)d_in[5];
  float* out = (float*)d_out;

  f16* y16      = (f16*)d_ws;               // 52,428,800 halves (104.9 MB)
  f16* w16      = y16 + 52428800;           //  5,308,416 halves ( 10.6 MB)
  float* p4     = (float*)(w16 + 5308416);  //  4 x 4,718,592 f32 ( 75.5 MB)
  float* u      = p4 + 4 * 4718592;         //  4,718,592 f32     ( 18.9 MB)
  f16* rw16     = (f16*)(u + 4718592);      //  1,474,560 halves  (  2.9 MB)
  float* logits = (float*)(rw16 + 1474560); //  5,120 f32

  conv1_kernel<<<dim3(512, 4), 256, 0, stream>>>(x, conv_w, conv_b, y16);
  wprep_kernel<<<2592, 256, 0, stream>>>(prim_w, w16);
  wprep_rw<<<720, 256, 0, stream>>>(route_w, rw16);
  conv2_mfma<<<1152, 256, 0, stream>>>(y16, w16, p4);
  squash_kernel<<<(512 * 1152 + 255) / 256, 256, 0, stream>>>(p4, prim_b, u);
  routing_kernel<<<dim3(512, 10), 256, 0, stream>>>(u, rw16, logits);
  out_softmax_kernel<<<2, 256, 0, stream>>>(logits, out);
}

// Round 11
// 663.323 us; speedup vs baseline: 3.9813x; 1.0345x over previous
//
#include <hip/hip_runtime.h>
#include <cstddef>
#include <cstdint>

typedef _Float16 f16;
typedef _Float16 f16x4 __attribute__((ext_vector_type(4)));
typedef _Float16 f16x8 __attribute__((ext_vector_type(8)));
typedef float f32x4 __attribute__((ext_vector_type(4)));
typedef float f32x16 __attribute__((ext_vector_type(16)));

#define AS1 __attribute__((address_space(1)))
#define AS3 __attribute__((address_space(3)))

// ---------------------------------------------------------------------------
// CapsuleNet forward.
// conv2 = f16 MFMA implicit GEMM, split-K=4, block 128oc x 128n, wave 64x64.
//   B: LDS 32KB dbuf (gload_lds, XOR-swizzle).  A: L2->registers, static
//   unroll-by-2 double-buffer (a0/a1 — constant indices only, rule #20).
// ws: y16 f16[512*400*256] | w16t f16[81*32*256*8] | p4 f32[4][512*256*36]
//     | u f32[512*1152*8] | rw16 f16[10*1152*128] | logits f32[5120]
// ---------------------------------------------------------------------------

__device__ __forceinline__ float wave_max(float v) {
#pragma unroll
  for (int m = 1; m < 64; m <<= 1) v = fmaxf(v, __shfl_xor(v, m, 64));
  return v;
}
__device__ __forceinline__ float wave_sum(float v) {
#pragma unroll
  for (int m = 1; m < 64; m <<= 1) v += __shfl_xor(v, m, 64);
  return v;
}

// ---------------- Conv1: x(512,1,28,28) * w(256,1,9,9) + b -> y16[b][px][ic] f16
__global__ __launch_bounds__(256) void conv1_kernel(
    const float* __restrict__ x, const float* __restrict__ w,
    const float* __restrict__ bias, f16* __restrict__ y16) {
  const int b   = blockIdx.x;
  const int oc0 = blockIdx.y * 64;
  const int t   = threadIdx.x;
  const int tx  = t & 15;
  const int ty  = t >> 4;
  const int oxg = ty & 3;
  const int oy0 = ty >> 2;

  __shared__ float x_s[784];
  __shared__ float w_s[81][68];

  for (int idx = t; idx < 784; idx += 256) x_s[idx] = x[b * 784 + idx];
  for (int idx = t; idx < 64 * 81; idx += 256) {
    const int oc_l = idx / 81, k = idx % 81;
    w_s[k][oc_l] = w[(oc0 + oc_l) * 81 + k];
  }
  __syncthreads();

  float bz[4];
#pragma unroll
  for (int j = 0; j < 4; ++j) bz[j] = bias[oc0 + tx * 4 + j];

  for (int m = 0; m < 5; ++m) {
    const int oy = oy0 + m * 4;
    float acc[4][5];
#pragma unroll
    for (int j = 0; j < 4; ++j)
#pragma unroll
      for (int pp = 0; pp < 5; ++pp) acc[j][pp] = 0.f;

#pragma unroll
    for (int ky = 0; ky < 9; ++ky) {
      float xv[13];
      const int base = (oy + ky) * 28 + oxg * 5;
#pragma unroll
      for (int jj = 0; jj < 13; ++jj) xv[jj] = x_s[base + jj];
#pragma unroll
      for (int kx = 0; kx < 9; ++kx) {
        const float4 w4 = *reinterpret_cast<const float4*>(&w_s[ky * 9 + kx][tx * 4]);
#pragma unroll
        for (int pp = 0; pp < 5; ++pp) {
          const float xval = xv[kx + pp];
          acc[0][pp] += w4.x * xval;
          acc[1][pp] += w4.y * xval;
          acc[2][pp] += w4.z * xval;
          acc[3][pp] += w4.w * xval;
        }
      }
    }
#pragma unroll
    for (int pp = 0; pp < 5; ++pp) {
      f16x4 st;
#pragma unroll
      for (int j = 0; j < 4; ++j) st[j] = (f16)(acc[j][pp] + bz[j]);
      const int px = oy * 20 + oxg * 5 + pp;
      *(f16x4*)&y16[((size_t)b * 400 + px) * 256 + oc0 + tx * 4] = st;
    }
  }
}

// ---------------- weight prep: prim_w[oc][ic][81] f32 ->
//   w16t[kk81][chunk32][oc256][8]  (R7-validated layout; A-frag = 16B/lane)
__global__ __launch_bounds__(256) void wprep_kernel(const float* __restrict__ w,
                                                    f16* __restrict__ w16t) {
  const int idx = blockIdx.x * 256 + threadIdx.x;  // 81*32*256 = 663552
  const int kk  = idx >> 13;
  const int rem = idx & 8191;
  const int icg = rem >> 8;   // chunk 0..31
  const int oc  = rem & 255;
  f16x8 v;
#pragma unroll
  for (int j = 0; j < 8; ++j)
    v[j] = (f16)w[((size_t)(oc * 256 + icg * 8 + j)) * 81 + kk];
  *(f16x8*)&w16t[(((size_t)kk * 32 + icg) * 256 + oc) * 8] = v;
}

// ---------------- route_w prep: f32 -> f16
__global__ __launch_bounds__(256) void wprep_rw(const float* __restrict__ rw,
                                                f16* __restrict__ rw16) {
  const int idx = (blockIdx.x * 256 + threadIdx.x) * 8;
  const float4 a = *(const float4*)(rw + idx);
  const float4 b = *(const float4*)(rw + idx + 4);
  f16x8 v;
  v[0] = (f16)a.x; v[1] = (f16)a.y; v[2] = (f16)a.z; v[3] = (f16)a.w;
  v[4] = (f16)b.x; v[5] = (f16)b.y; v[6] = (f16)b.z; v[7] = (f16)b.w;
  *(f16x8*)&rw16[idx] = v;
}

// ---------------- Conv2 MFMA: B in LDS, A in registers (static 2-unroll)
__global__ __launch_bounds__(256, 3) void conv2_mfma(
    const f16* __restrict__ y16, const f16* __restrict__ w16t,
    float* __restrict__ p4) {
  const int h       = blockIdx.x;
  const int ntile   = h % 144;
  const int variant = h / 144;
  const int mtile   = variant >> 2;
  const int ks      = variant & 3;
  const int oc0     = mtile * 128;
  const int cicb    = ks * 64;

  const int tid  = threadIdx.x;
  const int lane = tid & 63;
  const int wave = tid >> 6;
  const int l31  = lane & 31;
  const int hi   = lane >> 5;
  const int wm   = wave >> 1;
  const int wn   = wave & 1;

  __shared__ char smem[32768];

  // ---- B staging (R6-validated): 16 row-groups of 8 rows, 4 gload_lds/wave
  const int lr   = lane >> 3;
  const int swz  = ((lane & 7) ^ (lr & 7)) * 8;
  const f16* bPtr[4];
  uint32_t bLoff[4];
#pragma unroll
  for (int q = 0; q < 4; ++q) {
    const int g  = wave * 4 + q;
    const int n  = ntile * 128 + g * 8 + lr;
    const int b  = n / 36;
    const int op = n - b * 36;
    const int oy = op / 6;
    const int ox = op - oy * 6;
    bPtr[q]  = y16 + ((size_t)b * 400 + 40 * oy + 2 * ox) * 256 + cicb + swz;
    bLoff[q] = (uint32_t)__builtin_amdgcn_readfirstlane(g * 1024);
  }

  // ---- A addressing (R7-validated): halves offset
  const int aBase = (ks * 8 + hi) * 2048 + (oc0 + wm * 64 + l31) * 8;

  f32x16 acc00, acc01, acc10, acc11;
#pragma unroll
  for (int r = 0; r < 16; ++r) {
    acc00[r] = 0.f; acc01[r] = 0.f; acc10[r] = 0.f; acc11[r] = 0.f;
  }

  const int rowB  = (wn * 64 + l31) * 128;
  const int sbase = l31 & 7;

#define STAGE_B(bb, kkn)                                                      \
  do {                                                                        \
    const int ky_ = (kkn) / 9, kx_ = (kkn) - ky_ * 9;                         \
    const int koffB_ = (20 * ky_ + kx_) * 256;                                \
    _Pragma("unroll") for (int q = 0; q < 4; ++q)                             \
        __builtin_amdgcn_global_load_lds(                                     \
            (const AS1 uint32_t*)(bPtr[q] + koffB_),                          \
            (AS3 uint32_t*)((AS3 char*)smem + (bb) + bLoff[q]), 16, 0, 0);    \
  } while (0)

#define LOAD_A(Areg, kkn)                                                     \
  do {                                                                        \
    const f16* ap_ = w16t + (size_t)(kkn)*65536 + aBase;                      \
    _Pragma("unroll") for (int kc = 0; kc < 4; ++kc) {                        \
      Areg[kc * 2 + 0] = *(const f16x8*)(ap_ + kc * 4096);                    \
      Areg[kc * 2 + 1] = *(const f16x8*)(ap_ + kc * 4096 + 256);              \
    }                                                                         \
  } while (0)

#define COMPUTE(bufbase, Areg)                                                \
  do {                                                                        \
    const char* bufp_ = smem + (bufbase);                                     \
    _Pragma("unroll") for (int kc = 0; kc < 4; ++kc) {                        \
      const int sw_ = (((kc * 2 + hi) ^ sbase) << 4);                         \
      const f16x8 b0_ = *(const f16x8*)(bufp_ + rowB + sw_);                  \
      const f16x8 b1_ = *(const f16x8*)(bufp_ + rowB + 32 * 128 + sw_);       \
      acc00 = __builtin_amdgcn_mfma_f32_32x32x16_f16(Areg[kc * 2 + 0], b0_,   \
                                                     acc00, 0, 0, 0);         \
      acc01 = __builtin_amdgcn_mfma_f32_32x32x16_f16(Areg[kc * 2 + 0], b1_,   \
                                                     acc01, 0, 0, 0);         \
      acc10 = __builtin_amdgcn_mfma_f32_32x32x16_f16(Areg[kc * 2 + 1], b0_,   \
                                                     acc10, 0, 0, 0);         \
      acc11 = __builtin_amdgcn_mfma_f32_32x32x16_f16(Areg[kc * 2 + 1], b1_,   \
                                                     acc11, 0, 0, 0);         \
    }                                                                         \
  } while (0)

  f16x8 a0[8], a1[8];
  STAGE_B(0, 0);      // 4 outstanding
  LOAD_A(a0, 0);      // 12 outstanding

  for (int it = 0; it < 40; ++it) {
    const int kkA = 2 * it;
    // phase A: kk = kkA (buf0, a0); prefetch kkA+1 -> buf1, a1
    STAGE_B(16384, kkA + 1);
    LOAD_A(a1, kkA + 1);
    __builtin_amdgcn_sched_barrier(0);
    asm volatile("s_waitcnt vmcnt(12)" ::: "memory");  // buf0+a0 landed
    __builtin_amdgcn_s_barrier();
    __builtin_amdgcn_s_setprio(1);
    COMPUTE(0, a0);
    __builtin_amdgcn_s_setprio(0);
    __builtin_amdgcn_s_barrier();
    // phase B: kk = kkA+1 (buf1, a1); prefetch kkA+2 -> buf0, a0
    STAGE_B(0, kkA + 2);
    LOAD_A(a0, kkA + 2);
    __builtin_amdgcn_sched_barrier(0);
    asm volatile("s_waitcnt vmcnt(12)" ::: "memory");  // buf1+a1 landed
    __builtin_amdgcn_s_barrier();
    __builtin_amdgcn_s_setprio(1);
    COMPUTE(16384, a1);
    __builtin_amdgcn_s_setprio(0);
    __builtin_amdgcn_s_barrier();
  }
  // kk = 80 (staged into buf0/a0 by last phase B)
  asm volatile("s_waitcnt vmcnt(0)" ::: "memory");
  __builtin_amdgcn_s_barrier();
  COMPUTE(0, a0);

#undef STAGE_B
#undef LOAD_A
#undef COMPUTE

  // ---- epilogue: C[m][n]: oc_m = (r&3)+8*(r>>2)+4*hi, n = l31
  float* pk = p4 + (size_t)ks * 4718592;
#pragma unroll
  for (int af = 0; af < 2; ++af) {
#pragma unroll
    for (int bf = 0; bf < 2; ++bf) {
      const f32x16 a = af ? (bf ? acc11 : acc10) : (bf ? acc01 : acc00);
      const int n  = ntile * 128 + wn * 64 + bf * 32 + l31;
      const int b  = n / 36;
      const int op = n - b * 36;
      float* pb = pk + (size_t)b * 9216 + op;
      const int ocb = oc0 + wm * 64 + af * 32 + 4 * hi;
#pragma unroll
      for (int r = 0; r < 16; ++r) {
        const int oc = ocb + (r & 3) + 8 * (r >> 2);
        pb[oc * 36] = a[r];
      }
    }
  }
}

// ---------------- squash: sum 4 K-partials + bias, squash -> u(512,1152,8)
__global__ __launch_bounds__(256) void squash_kernel(const float* __restrict__ p4,
                                                     const float* __restrict__ bias,
                                                     float* __restrict__ u) {
  const int idx = blockIdx.x * 256 + threadIdx.x;
  if (idx >= 512 * 1152) return;
  const int b = idx / 1152;
  const int r = idx % 1152;
  const int c2 = r / 36;
  const int s  = r % 36;
  const size_t base = (size_t)b * 9216 + c2 * 36 + s;
  float tv[8];
  float sn = 0.f;
#pragma unroll
  for (int g = 0; g < 8; ++g) {
    const size_t off = base + (size_t)g * 32 * 36;
    float t = p4[off] + p4[off + 4718592] + p4[off + 2 * 4718592] +
              p4[off + 3 * 4718592] + bias[g * 32 + c2];
    tv[g] = t;
    sn += t * t;
  }
  const float scale = sn / ((1.f + sn) * sqrtf(sn));
  float* up = u + (size_t)idx * 8;
#pragma unroll
  for (int g = 0; g < 8; ++g) up[g] = tv[g] * scale;
}

// ---------------- routing: per (b,c) block; route_w in f16.
__global__ __launch_bounds__(256) void routing_kernel(const float* __restrict__ u,
                                                      const f16* __restrict__ rw16,
                                                      float* __restrict__ logits) {
  const int b    = blockIdx.x;
  const int c    = blockIdx.y;
  const int t    = threadIdx.x;
  const int og   = t & 3;
  const int rg   = t >> 2;
  const int lane = t & 63;
  const int wid  = t >> 6;

  __shared__ float u_s[1152 * 9];
  __shared__ float blog_s[1152];
  __shared__ float red[8];
  __shared__ float sred[64];

  for (int idx = t; idx < 1152 * 8; idx += 256)
    u_s[(idx >> 3) * 9 + (idx & 7)] = u[(size_t)b * 9216 + idx];
  for (int idx = t; idx < 1152; idx += 256) blog_s[idx] = 0.f;
  __syncthreads();

  float pr[18][4];
  const f16* rwc = rw16 + (size_t)c * 1152 * 128;
#pragma unroll
  for (int k = 0; k < 18; ++k) {
    const int r = rg + 64 * k;
    float a0 = 0.f, a1 = 0.f, a2 = 0.f, a3 = 0.f;
#pragma unroll
    for (int i = 0; i < 8; ++i) {
      const float uv = u_s[r * 9 + i];
      const f16x4 w4 = *reinterpret_cast<const f16x4*>(rwc + (size_t)r * 128 + i * 16 + og * 4);
      a0 += uv * (float)w4[0]; a1 += uv * (float)w4[1];
      a2 += uv * (float)w4[2]; a3 += uv * (float)w4[3];
    }
    pr[k][0] = a0; pr[k][1] = a1; pr[k][2] = a2; pr[k][3] = a3;
  }

  float sn = 0.f;
  float vj[4] = {0.f, 0.f, 0.f, 0.f};

  for (int it = 0; it < 3; ++it) {
    float lmax = -3.4e38f;
    for (int idx = t; idx < 1152; idx += 256) lmax = fmaxf(lmax, blog_s[idx]);
    lmax = wave_max(lmax);
    if (lane == 0) red[wid] = lmax;
    __syncthreads();
    const float gmax = fmaxf(fmaxf(red[0], red[1]), fmaxf(red[2], red[3]));
    float lsum = 0.f;
    for (int idx = t; idx < 1152; idx += 256) lsum += expf(blog_s[idx] - gmax);
    lsum = wave_sum(lsum);
    if (lane == 0) red[4 + wid] = lsum;
    __syncthreads();
    const float ginv = 1.f / (red[4] + red[5] + red[6] + red[7]);

    float sp0 = 0.f, sp1 = 0.f, sp2 = 0.f, sp3 = 0.f;
#pragma unroll
    for (int k = 0; k < 18; ++k) {
      const int r = rg + 64 * k;
      const float pb = expf(blog_s[r] - gmax) * ginv;
      sp0 += pr[k][0] * pb; sp1 += pr[k][1] * pb;
      sp2 += pr[k][2] * pb; sp3 += pr[k][3] * pb;
    }
#pragma unroll
    for (int m = 4; m < 64; m <<= 1) {
      sp0 += __shfl_xor(sp0, m, 64);
      sp1 += __shfl_xor(sp1, m, 64);
      sp2 += __shfl_xor(sp2, m, 64);
      sp3 += __shfl_xor(sp3, m, 64);
    }
    if (lane < 4) {
      sred[wid * 16 + lane * 4 + 0] = sp0;
      sred[wid * 16 + lane * 4 + 1] = sp1;
      sred[wid * 16 + lane * 4 + 2] = sp2;
      sred[wid * 16 + lane * 4 + 3] = sp3;
    }
    __syncthreads();

    sn = 0.f;
#pragma unroll
    for (int o = 0; o < 16; ++o) {
      const float sv = sred[o] + sred[16 + o] + sred[32 + o] + sred[48 + o];
      sn += sv * sv;
    }
    const float scale = sn / ((1.f + sn) * sqrtf(sn));
#pragma unroll
    for (int j = 0; j < 4; ++j) {
      const int o = og * 4 + j;
      vj[j] = (sred[o] + sred[16 + o] + sred[32 + o] + sred[48 + o]) * scale;
    }

    if (it < 2) {
#pragma unroll
      for (int k = 0; k < 18; ++k) {
        float bp = pr[k][0] * vj[0] + pr[k][1] * vj[1] + pr[k][2] * vj[2] + pr[k][3] * vj[3];
        bp += __shfl_xor(bp, 1, 64);
        bp += __shfl_xor(bp, 2, 64);
        if (og == 0) blog_s[rg + 64 * k] += bp;
      }
      __syncthreads();
    }
  }
  if (t == 0) logits[b * 10 + c] = sn / (1.f + sn);
}

// ---------------- final softmax over 10 classes
__global__ __launch_bounds__(256) void out_softmax_kernel(const float* __restrict__ logits,
                                                          float* __restrict__ out) {
  const int b = blockIdx.x * 256 + threadIdx.x;
  if (b >= 512) return;
  float l[10];
  float mx = -3.4e38f;
#pragma unroll
  for (int cc = 0; cc < 10; ++cc) {
    l[cc] = logits[b * 10 + cc];
    mx = fmaxf(mx, l[cc]);
  }
  float s = 0.f;
#pragma unroll
  for (int cc = 0; cc < 10; ++cc) {
    l[cc] = expf(l[cc] - mx);
    s += l[cc];
  }
  const float inv = 1.f / s;
#pragma unroll
  for (int cc = 0; cc < 10; ++cc) out[b * 10 + cc] = l[cc] * inv;
}

extern "C" void kernel_launch(void* const* d_in, const int* in_sizes, int n_in,
                              void* d_out, int out_size, void* d_ws, size_t ws_size,
                              hipStream_t stream) {
  const float* x       = (const float*)d_in[0];
  const float* conv_w  = (const float*)d_in[1];
  const float* conv_b  = (const float*)d_in[2];
  const float* prim_w  = (const float*)d_in[3];
  const float* prim_b  = (const float*)d_in[4];
  const float* route_w = (const float*)d_in[5];
  float* out = (float*)d_out;

  f16* y16      = (f16*)d_ws;               // 52,428,800 halves (104.9 MB)
  f16* w16t     = y16 + 52428800;           //  5,308,416 halves ( 10.6 MB)
  float* p4     = (float*)(w16t + 5308416); //  4 x 4,718,592 f32 ( 75.5 MB)
  float* u      = p4 + 4 * 4718592;         //  4,718,592 f32     ( 18.9 MB)
  f16* rw16     = (f16*)(u + 4718592);      //  1,474,560 halves  (  2.9 MB)
  float* logits = (float*)(rw16 + 1474560); //  5,120 f32

  conv1_kernel<<<dim3(512, 4), 256, 0, stream>>>(x, conv_w, conv_b, y16);
  wprep_kernel<<<2592, 256, 0, stream>>>(prim_w, w16t);
  wprep_rw<<<720, 256, 0, stream>>>(route_w, rw16);
  conv2_mfma<<<1152, 256, 0, stream>>>(y16, w16t, p4);
  squash_kernel<<<(512 * 1152 + 255) / 256, 256, 0, stream>>>(p4, prim_b, u);
  routing_kernel<<<dim3(512, 10), 256, 0, stream>>>(u, rw16, logits);
  out_softmax_kernel<<<2, 256, 0, stream>>>(logits, out);
}